// Round 14
// baseline (157.957 us; speedup 1.0000x reference)
//
#include <hip/hip_runtime.h>
#include <math.h>

#pragma clang fp contract(off)

constexpr int NB  = 16;    // batch
constexpr int NR  = 4096;  // rois per image
constexpr int NC  = 81;    // classes (incl. background)
constexpr int NCM1 = NC - 1;              // foreground classes
constexpr int KK  = 200;   // per-class candidate cap == max_total
constexpr int CAP = 4096;  // max kept entries per image
constexpr int WCAP = 256;  // per-wave candidate cap (observed per-class max ~50)
constexpr int TCHUNK = 256;
constexpr int NCHUNK = CAP / TCHUNK;      // 16 blocks per image
constexpr float SCORE_TH = 0.5f;
constexpr float IOU_TH   = 0.5f;
constexpr float EPSF     = 1e-8f;

struct SK { float s; int key; };   // 8B packed (score, cls*KK + prenms_rank)

__device__ __forceinline__ void decode_box(const float4& a, const float4& d,
                                           float& y1, float& x1, float& y2, float& x2) {
    float ah  = a.z - a.x;
    float aw  = a.w - a.y;
    float acy = a.x + 0.5f * ah;
    float acx = a.y + 0.5f * aw;
    float dy = d.x * 0.1f, dx = d.y * 0.1f;
    float dh = d.z * 0.2f, dw = d.w * 0.2f;
    float bh  = expf(dh) * ah;
    float bw  = expf(dw) * aw;
    float bcy = dy * ah + acy;
    float bcx = dx * aw + acx;
    y1 = bcy - 0.5f * bh;
    x1 = bcx - 0.5f * bw;
    y2 = y1 + bh;
    x2 = x1 + bw;
}

// One block per image, 1024 threads (16 waves).
// Phase 1 (block-wide): staged argmax of probs -> pscore/pcls in LDS.
// Phase 2 (wave-independent, barrier-free): wave w handles classes c-1 ≡ w
// (mod 16): ballot-compact candidates -> lane-parallel stable rank ->
// decode top-200 -> register wave-NMS -> ballot-compacted global write.
// kcnt written unconditionally; no init pass; no global atomics.
__global__ __launch_bounds__(1024)
void k_fused(const float* __restrict__ roi,
             const float* __restrict__ deltas,
             const float* __restrict__ probs,
             int* __restrict__ kcnt,
             SK* __restrict__ sk_seg,
             float4* __restrict__ fbox_seg) {
    __shared__ float4 stage4[256 * NC / 4];   // 82944 B (phase1 stage / phase2 scratch)
    __shared__ float  pscore[NR];             // 16 KB
    __shared__ int    pcls[NR];               // 16 KB

    const int b = blockIdx.x, tid = threadIdx.x;
    const int lane = tid & 63, w = tid >> 6;
    const unsigned long long lmask_lt = (1ull << lane) - 1ull;

    // ---- phase 1: classify 4096 rows in 16 megatiles of 256 rows ----
    for (int t = 0; t < 16; ++t) {
        __syncthreads();   // previous tile fully consumed
        const float4* src = (const float4*)(probs + ((size_t)b * NR + t * 256) * NC);
        for (int v = tid; v < 256 * NC / 4; v += 1024) stage4[v] = src[v];
        __syncthreads();
        int g = tid >> 2, j = tid & 3;
        const float* row = (const float*)stage4 + g * NC;
        float m = -1.0f;
        int am = 127;
        for (int c = j; c < NC; c += 4) {
            float v = row[c];
            if (v > m) { m = v; am = c; }            // first-max within subset
        }
        for (int mask = 1; mask <= 2; mask <<= 1) {  // tie -> smaller idx (jnp.argmax)
            float om = __shfl_xor(m, mask);
            int   oi = __shfl_xor(am, mask);
            if (om > m || (om == m && oi < am)) { m = om; am = oi; }
        }
        if (j == 0) {
            int r = t * 256 + g;
            pscore[r] = m;
            pcls[r] = (am != 0 && m > SCORE_TH) ? am : 0;
        }
    }
    __syncthreads();   // pscore/pcls complete; stage4 free for phase-2 scratch

    // ---- phase 2: wave-independent per-class pipeline ----
    float2* wcand = (float2*)stage4 + (size_t)w * WCAP;          // 2 KB/wave
    float2* wrank = (float2*)stage4 + 16 * WCAP + (size_t)w * WCAP;

    for (int cc = 0; cc < 5; ++cc) {
        int cm1 = w + cc * 16;          // 0..79
        int c = cm1 + 1;
        int outbase = b * NCM1 + cm1;

        // ballot-compact candidates of class c (order = roi ascending)
        int cnt = 0;
        for (int base = 0; base < NR; base += 64) {
            int r = base + lane;
            bool pred = (pcls[r] == c);
            unsigned long long bal = __ballot(pred);
            if (pred) {
                int pos = cnt + __popcll(bal & lmask_lt);
                if (pos < WCAP) wcand[pos] = make_float2(pscore[r], (float)r);
            }
            cnt += __popcll(bal);
        }
        int Mc = cnt < WCAP ? cnt : WCAP;
        if (Mc == 0) {
            if (lane == 0) kcnt[outbase] = 0;
            continue;                    // wave-uniform
        }
        int L = Mc < KK ? Mc : KK;

        // stable rank by (score desc, roi asc) — lax.top_k order
        #pragma unroll
        for (int s = 0; s < 4; ++s) {
            int i = s * 64 + lane;
            if (i < Mc) {
                float2 me = wcand[i];
                int rank = 0;
                for (int jj = 0; jj < Mc; ++jj) {
                    float2 v = wcand[jj];
                    rank += (int)((v.x > me.x) | ((v.x == me.x) & (v.y < me.y)));
                }
                if (rank < KK) wrank[rank] = me;     // ranks unique
            }
        }

        // load ranked items; decode boxes (only survivors)
        float bsc[4], by1[4], bx1[4], by2[4], bx2[4], bar_[4];
        int kmask = 0;
        #pragma unroll
        for (int s = 0; s < 4; ++s) {
            int rho = s * 64 + lane;
            if (rho < L) {
                float2 me = wrank[rho];
                int r = (int)me.y;
                float4 a = ((const float4*)roi)[(size_t)b * NR + r];
                float4 d = *(const float4*)(deltas + (((size_t)b * NR + r) * NC + c) * 4);
                float y1, x1, y2, x2;
                decode_box(a, d, y1, x1, y2, x2);
                bsc[s] = me.x;
                by1[s] = y1; bx1[s] = x1; by2[s] = y2; bx2[s] = x2;
                bar_[s] = fmaxf(y2 - y1, 0.f) * fmaxf(x2 - x1, 0.f);
                kmask |= 1 << s;
            }
        }

        // greedy wave-NMS; slot-unrolled so register indices stay static
        #pragma unroll
        for (int si = 0; si < 4; ++si) {
            int iend = (si + 1) * 64 < L ? (si + 1) * 64 : L;
            for (int i = si * 64; i < iend; ++i) {
                int oi = i & 63;
                int keep_i = (__shfl(kmask, oi) >> si) & 1;   // uniform
                if (!keep_i) continue;
                float yi1 = __shfl(by1[si], oi), xi1 = __shfl(bx1[si], oi);
                float yi2 = __shfl(by2[si], oi), xi2 = __shfl(bx2[si], oi);
                float ai  = __shfl(bar_[si], oi);
                #pragma unroll
                for (int s = 0; s < 4; ++s) {
                    int jj = s * 64 + lane;
                    if (jj > i && ((kmask >> s) & 1)) {
                        float yy1 = fmaxf(yi1, by1[s]), xx1 = fmaxf(xi1, bx1[s]);
                        float yy2 = fminf(yi2, by2[s]), xx2 = fminf(xi2, bx2[s]);
                        float inter = fmaxf(yy2 - yy1, 0.f) * fmaxf(xx2 - xx1, 0.f);
                        float uni = ai + bar_[s] - inter;
                        if (inter / (uni + EPSF) > IOU_TH) kmask &= ~(1 << s);
                    }
                }
            }
        }

        // ballot-prefix compaction; sk at post-NMS pos, fbox at pre-NMS rank
        int tot = 0, mypos[4];
        #pragma unroll
        for (int s = 0; s < 4; ++s) {
            unsigned long long bal = __ballot((kmask >> s) & 1);
            mypos[s] = tot + __popcll(bal & lmask_lt);
            tot += __popcll(bal);
        }
        size_t sb = (size_t)outbase * KK;
        #pragma unroll
        for (int s = 0; s < 4; ++s) {
            int rho = s * 64 + lane;
            if ((kmask >> s) & 1) {
                sk_seg[sb + mypos[s]].s = bsc[s];
                sk_seg[sb + mypos[s]].key = c * KK + rho;
                fbox_seg[sb + rho] = make_float4(by1[s], bx1[s], by2[s], bx2[s]);
            }
        }
        if (lane == 0) kcnt[outbase] = tot;
    }
}

// NCHUNK blocks per image: prefix over 80 class counts -> gather compact
// (score,key) list into LDS (binary-search segment lookup) -> each thread
// ranks ONE entry (float4 = 2 entries/read) -> direct scatter write (ranks
// unique & dense). Box fetched by key: fg class cm1 = ke/KK - 1, i = ke%KK.
__global__ void k_topk(const int* __restrict__ kcnt,
                       const SK* __restrict__ sk_seg,
                       const float4* __restrict__ fbox_seg,
                       float* __restrict__ out) {
    int b = blockIdx.x / NCHUNK, chunk = blockIdx.x % NCHUNK;
    const int tid = threadIdx.x;

    __shared__ int pfx[NCM1 + 1];
    __shared__ SK  sL[CAP];   // 32 KB packed (score,key)

    if (tid < NCM1) pfx[tid + 1] = kcnt[b * NCM1 + tid];
    if (tid == 0) pfx[0] = 0;
    __syncthreads();
    if (tid == 0) {
        int run = 0;
        for (int s = 1; s <= NCM1; ++s) { run += pfx[s]; pfx[s] = run; }
    }
    __syncthreads();
    int M = pfx[NCM1];

    float* obox = out + (size_t)b * KK * 4;
    float* olbl = out + (size_t)NB * KK * 4 + (size_t)b * KK;
    float* osc  = out + (size_t)NB * KK * 5 + (size_t)b * KK;

    if (chunk == 0) {   // zero the unwritten tail every call (deterministic output)
        int Mi = M < KK ? M : KK;
        for (int i = Mi + tid; i < KK; i += 256) {
            obox[i * 4 + 0] = 0.f; obox[i * 4 + 1] = 0.f;
            obox[i * 4 + 2] = 0.f; obox[i * 4 + 3] = 0.f;
            olbl[i] = 0.f; osc[i] = 0.f;
        }
    }
    if (chunk * TCHUNK >= M) return;

    // gather compact list: binary search segment for each compact index
    for (int i = tid; i < M; i += 256) {
        int lo = 0, hi = NCM1 - 1;        // find lo: pfx[lo] <= i < pfx[lo+1]
        while (lo < hi) {
            int mid = (lo + hi + 1) >> 1;
            if (pfx[mid] <= i) lo = mid; else hi = mid - 1;
        }
        int k = i - pfx[lo];
        sL[i] = sk_seg[((size_t)b * NCM1 + lo) * KK + k];
    }
    __syncthreads();

    int e = chunk * TCHUNK + tid;
    if (e >= M) return;
    float se = sL[e].s; int ke = sL[e].key;
    int rank = 0;
    const float4* p4 = (const float4*)sL;   // 2 SK per float4
    int npair = M >> 1;
    #pragma unroll 4
    for (int p = 0; p < npair; ++p) {
        float4 v = p4[p];
        int k0 = __float_as_int(v.y), k1 = __float_as_int(v.w);
        rank += (int)((v.x > se) | ((v.x == se) & (k0 < ke)));
        rank += (int)((v.z > se) | ((v.z == se) & (k1 < ke)));
    }
    if (M & 1) {
        float sj = sL[M - 1].s; int kj = sL[M - 1].key;
        rank += (int)((sj > se) | ((sj == se) & (kj < ke)));
    }
    if (rank < KK) {
        int cm1 = ke / KK - 1, ipre = ke % KK;
        float4 bx = fbox_seg[((size_t)b * NCM1 + cm1) * KK + ipre];
        obox[rank * 4 + 0] = fminf(fmaxf(bx.x, 0.f), 1.f);
        obox[rank * 4 + 1] = fminf(fmaxf(bx.y, 0.f), 1.f);
        obox[rank * 4 + 2] = fminf(fmaxf(bx.z, 0.f), 1.f);
        obox[rank * 4 + 3] = fminf(fmaxf(bx.w, 0.f), 1.f);
        olbl[rank] = (float)(ke / KK);
        osc[rank]  = se;
    }
}

extern "C" void kernel_launch(void* const* d_in, const int* in_sizes, int n_in,
                              void* d_out, int out_size, void* d_ws, size_t ws_size,
                              hipStream_t stream) {
    const float* roi    = (const float*)d_in[0];
    const float* deltas = (const float*)d_in[1];
    const float* probs  = (const float*)d_in[2];
    float* out = (float*)d_out;

    char* base = (char*)d_ws;
    int*    kcnt     = (int*)base;                               // 16*80 ints
    SK*     sk_seg   = (SK*)(base + 16384);                      // 16*80*200*8  = 2.05 MB
    float4* fbox_seg = (float4*)(base + 16384 + 2097152);        // 16*80*200*16 = 4.1 MB

    k_fused<<<NB, 1024, 0, stream>>>(roi, deltas, probs, kcnt, sk_seg, fbox_seg);
    k_topk<<<NB * NCHUNK, 256, 0, stream>>>(kcnt, sk_seg, fbox_seg, out);
}

// Round 15
// 150.752 us; speedup vs baseline: 1.0478x; 1.0478x over previous
//
#include <hip/hip_runtime.h>
#include <math.h>

#pragma clang fp contract(off)

constexpr int NB  = 16;    // batch
constexpr int NR  = 4096;  // rois per image
constexpr int NC  = 81;    // classes (incl. background)
constexpr int NCM1 = NC - 1;              // foreground classes
constexpr int KK  = 200;   // per-class candidate cap == max_total
constexpr int ROWS_PER_BLK = 64;
constexpr int CHUNKS = NR / ROWS_PER_BLK;     // 64 chunks per image
constexpr int GRID = NB * NR / ROWS_PER_BLK;  // 1024 classify blocks
constexpr int WCAP = 512;                     // per-wave candidate cap
constexpr float SCORE_TH = 0.5f;
constexpr float IOU_TH   = 0.5f;
constexpr float EPSF     = 1e-8f;

struct SK { float s; int key; };   // 8B packed (score, cls*KK + prenms_rank)

__device__ __forceinline__ void decode_box(const float4& a, const float4& d,
                                           float& y1, float& x1, float& y2, float& x2) {
    float ah  = a.z - a.x;
    float aw  = a.w - a.y;
    float acy = a.x + 0.5f * ah;
    float acx = a.y + 0.5f * aw;
    float dy = d.x * 0.1f, dx = d.y * 0.1f;
    float dh = d.z * 0.2f, dw = d.w * 0.2f;
    float bh  = expf(dh) * ah;
    float bw  = expf(dw) * aw;
    float bcy = dy * ah + acy;
    float bcx = dx * aw + acx;
    y1 = bcy - 0.5f * bh;
    x1 = bcx - 0.5f * bw;
    y2 = y1 + bh;
    x2 = x1 + bw;
}

// 4 threads/ROI, 64 ROIs/block, 1024 blocks (full device for the 21MB read).
// Emits compact per-chunk candidates (cls, score, roi). No decode here.
__global__ void k_classify(const float* __restrict__ probs,
                           int* __restrict__ blk_cnt,
                           int* __restrict__ scls,
                           float2* __restrict__ ssr) {
    __shared__ float lp[ROWS_PER_BLK * NC];   // 20736 B
    __shared__ int wcnt[4], wbase[4];
    const int bid = blockIdx.x, tid = threadIdx.x;

    const float4* src = (const float4*)(probs + (size_t)bid * ROWS_PER_BLK * NC);
    float4* dst = (float4*)lp;
    for (int v = tid; v < ROWS_PER_BLK * NC / 4; v += 256) dst[v] = src[v];
    __syncthreads();

    int g = tid >> 2;               // row within block
    int j = tid & 3;                // sub-lane within row group
    const float* row = lp + g * NC;
    float m = -1.0f;
    int am = 127;
    for (int c = j; c < NC; c += 4) {
        float v = row[c];
        if (v > m) { m = v; am = c; }            // first-max within subset
    }
    for (int mask = 1; mask <= 2; mask <<= 1) {  // tie -> smaller idx (jnp.argmax)
        float om = __shfl_xor(m, mask);
        int   oi = __shfl_xor(am, mask);
        if (om > m || (om == m && oi < am)) { m = om; am = oi; }
    }

    bool pred = (j == 0) && (am != 0) && (m > SCORE_TH);
    unsigned long long bal = __ballot(pred);
    int lane = tid & 63, w = tid >> 6;
    if (lane == 0) wcnt[w] = __popcll(bal);
    __syncthreads();
    if (tid == 0) {
        int run = 0;
        for (int i = 0; i < 4; ++i) { wbase[i] = run; run += wcnt[i]; }
        blk_cnt[bid] = run;                      // unconditional: no init pass
    }
    __syncthreads();

    if (pred) {
        int pos = wbase[w] + __popcll(bal & ((1ull << lane) - 1ull));
        int r = bid * ROWS_PER_BLK + g;
        int idx = bid * ROWS_PER_BLK + pos;      // == b*NR + chunk*64 + pos
        scls[idx] = am;
        ssr[idx]  = make_float2(m, (float)(r & (NR - 1)));   // roi exact in f32
    }
}

// One block per image, 1024 threads (16 waves). Reads only ~100KB.
// A: dense candidate lists in LDS (chunk-prefix; roi-ascending order).
// B: wave w owns classes cm1 ≡ w (mod 16): ballot-compact -> LDS rank ->
//    decode survivors -> register wave-NMS -> fixed global segments.
// C: block prefix over 80 kept-counts -> gather (L1-coherent same-block
//    global) -> vectorized stable rank -> output + tail zero.
__global__ __launch_bounds__(1024)
void k_finish(const float* __restrict__ roi,
              const float* __restrict__ deltas,
              const int* __restrict__ blk_cnt,
              const int* __restrict__ scls,
              const float2* __restrict__ ssr,
              SK* __restrict__ sk_seg,
              float4* __restrict__ fbox_seg,
              float* __restrict__ out) {
    __shared__ int ccnt[CHUNKS];
    __shared__ int cpfx[CHUNKS + 1];
    union U {
        struct { float lsc[NR]; int lck[NR]; } a;   // phase A/B: 32 KB
        SK sL[NR];                                   // phase C: 32 KB
    };
    __shared__ U u;
    __shared__ float2 wcand[16][WCAP];   // 64 KB
    __shared__ float2 wrank[16][KK];     // 25.6 KB
    __shared__ int kcnt_l[NCM1];
    __shared__ int pfx[NCM1 + 1];

    const int b = blockIdx.x, tid = threadIdx.x;
    const int lane = tid & 63, w = tid >> 6;
    const unsigned long long lmask_lt = (1ull << lane) - 1ull;

    // ---- phase A: dense candidate lists ----
    if (tid < CHUNKS) ccnt[tid] = blk_cnt[b * CHUNKS + tid];
    __syncthreads();
    if (tid == 0) {
        int run = 0;
        for (int c = 0; c < CHUNKS; ++c) { cpfx[c] = run; run += ccnt[c]; }
        cpfx[CHUNKS] = run;
    }
    __syncthreads();
    const int Mtot = cpfx[CHUNKS];   // <= NR

    for (int idx = tid; idx < NR; idx += 1024) {
        int chunk = idx >> 6, s = idx & 63;
        if (s < ccnt[chunk]) {
            float2 v = ssr[(size_t)b * NR + idx];
            int cls  = scls[(size_t)b * NR + idx];
            int dense = cpfx[chunk] + s;
            u.a.lsc[dense] = v.x;
            u.a.lck[dense] = (cls << 12) | (int)v.y;   // cls:7b | roi:12b
        }
    }
    __syncthreads();

    // ---- phase B: wave-independent per-class pipeline (no block barriers) ----
    for (int cc = 0; cc < 5; ++cc) {
        int cm1 = w + cc * 16;          // 0..79
        int c = cm1 + 1;
        int outbase = b * NCM1 + cm1;
        float2* wc = &wcand[w][0];

        // ballot-compact candidates of class c (dense order = roi ascending)
        int cnt = 0;
        for (int base = 0; base < Mtot; base += 64) {
            int i = base + lane;
            bool pred = (i < Mtot) && ((u.a.lck[i] >> 12) == c);
            unsigned long long bal = __ballot(pred);
            if (pred) {
                int pos = cnt + __popcll(bal & lmask_lt);
                if (pos < WCAP)
                    wc[pos] = make_float2(u.a.lsc[i], (float)(u.a.lck[i] & 0xFFF));
            }
            cnt += __popcll(bal);
        }
        int Mc = cnt < WCAP ? cnt : WCAP;
        if (Mc == 0) {
            if (lane == 0) kcnt_l[cm1] = 0;
            continue;                    // wave-uniform
        }
        int L = Mc < KK ? Mc : KK;

        // stable rank by (score desc, roi asc) — lax.top_k order
        for (int i = lane; i < Mc; i += 64) {
            float2 me = wc[i];
            int rank = 0;
            for (int jj = 0; jj < Mc; ++jj) {
                float2 v = wc[jj];
                rank += (int)((v.x > me.x) | ((v.x == me.x) & (v.y < me.y)));
            }
            if (rank < KK) wrank[w][rank] = me;      // ranks unique
        }

        // load ranked survivors; decode boxes (scattered, L3-hit)
        float bsc[4], by1[4], bx1[4], by2[4], bx2[4], bar_[4];
        int kmask = 0;
        #pragma unroll
        for (int s = 0; s < 4; ++s) {
            int rho = s * 64 + lane;
            if (rho < L) {
                float2 me = wrank[w][rho];
                int r = (int)me.y;
                float4 a = ((const float4*)roi)[(size_t)b * NR + r];
                float4 d = *(const float4*)(deltas + (((size_t)b * NR + r) * NC + c) * 4);
                float y1, x1, y2, x2;
                decode_box(a, d, y1, x1, y2, x2);
                bsc[s] = me.x;
                by1[s] = y1; bx1[s] = x1; by2[s] = y2; bx2[s] = x2;
                bar_[s] = fmaxf(y2 - y1, 0.f) * fmaxf(x2 - x1, 0.f);
                kmask |= 1 << s;
            }
        }

        // greedy wave-NMS; slot-unrolled (static register indices)
        #pragma unroll
        for (int si = 0; si < 4; ++si) {
            int iend = (si + 1) * 64 < L ? (si + 1) * 64 : L;
            for (int i = si * 64; i < iend; ++i) {
                int oi = i & 63;
                int keep_i = (__shfl(kmask, oi) >> si) & 1;   // uniform
                if (!keep_i) continue;
                float yi1 = __shfl(by1[si], oi), xi1 = __shfl(bx1[si], oi);
                float yi2 = __shfl(by2[si], oi), xi2 = __shfl(bx2[si], oi);
                float ai  = __shfl(bar_[si], oi);
                #pragma unroll
                for (int s = 0; s < 4; ++s) {
                    int jj = s * 64 + lane;
                    if (jj > i && ((kmask >> s) & 1)) {
                        float yy1 = fmaxf(yi1, by1[s]), xx1 = fmaxf(xi1, bx1[s]);
                        float yy2 = fminf(yi2, by2[s]), xx2 = fminf(xi2, bx2[s]);
                        float inter = fmaxf(yy2 - yy1, 0.f) * fmaxf(xx2 - xx1, 0.f);
                        float uni = ai + bar_[s] - inter;
                        if (inter / (uni + EPSF) > IOU_TH) kmask &= ~(1 << s);
                    }
                }
            }
        }

        // ballot-prefix compaction; sk at post-NMS pos, fbox at pre-NMS rank
        int tot = 0, mypos[4];
        #pragma unroll
        for (int s = 0; s < 4; ++s) {
            unsigned long long bal = __ballot((kmask >> s) & 1);
            mypos[s] = tot + __popcll(bal & lmask_lt);
            tot += __popcll(bal);
        }
        size_t sb = (size_t)outbase * KK;
        #pragma unroll
        for (int s = 0; s < 4; ++s) {
            int rho = s * 64 + lane;
            if ((kmask >> s) & 1) {
                sk_seg[sb + mypos[s]].s = bsc[s];
                sk_seg[sb + mypos[s]].key = c * KK + rho;
                fbox_seg[sb + rho] = make_float4(by1[s], bx1[s], by2[s], bx2[s]);
            }
        }
        if (lane == 0) kcnt_l[cm1] = tot;
    }
    __syncthreads();   // phase B complete; u.a dead -> u.sL reusable

    // ---- phase C: image-level stable top-200 ----
    if (tid == 0) {
        int run = 0;
        for (int s = 0; s < NCM1; ++s) { pfx[s] = run; run += kcnt_l[s]; }
        pfx[NCM1] = run;
    }
    __syncthreads();
    int M = pfx[NCM1];   // <= NR by construction (kept <= candidates <= NR)

    // gather compact (score,key) list (same-block global writes: L1-coherent)
    for (int i = tid; i < M; i += 1024) {
        int lo = 0, hi = NCM1 - 1;        // find lo: pfx[lo] <= i < pfx[lo+1]
        while (lo < hi) {
            int mid = (lo + hi + 1) >> 1;
            if (pfx[mid] <= i) lo = mid; else hi = mid - 1;
        }
        int k = i - pfx[lo];
        u.sL[i] = sk_seg[((size_t)b * NCM1 + lo) * KK + k];
    }
    __syncthreads();

    float* obox = out + (size_t)b * KK * 4;
    float* olbl = out + (size_t)NB * KK * 4 + (size_t)b * KK;
    float* osc  = out + (size_t)NB * KK * 5 + (size_t)b * KK;

    {   // zero the unwritten tail every call (deterministic output)
        int Mi = M < KK ? M : KK;
        for (int i = Mi + tid; i < KK; i += 1024) {
            obox[i * 4 + 0] = 0.f; obox[i * 4 + 1] = 0.f;
            obox[i * 4 + 2] = 0.f; obox[i * 4 + 3] = 0.f;
            olbl[i] = 0.f; osc[i] = 0.f;
        }
    }

    for (int e = tid; e < M; e += 1024) {
        float se = u.sL[e].s; int ke = u.sL[e].key;
        int rank = 0;
        const float4* p4 = (const float4*)u.sL;   // 2 SK per float4
        int npair = M >> 1;
        #pragma unroll 4
        for (int p = 0; p < npair; ++p) {
            float4 v = p4[p];
            int k0 = __float_as_int(v.y), k1 = __float_as_int(v.w);
            rank += (int)((v.x > se) | ((v.x == se) & (k0 < ke)));
            rank += (int)((v.z > se) | ((v.z == se) & (k1 < ke)));
        }
        if (M & 1) {
            float sj = u.sL[M - 1].s; int kj = u.sL[M - 1].key;
            rank += (int)((sj > se) | ((sj == se) & (kj < ke)));
        }
        if (rank < KK) {
            int cm1 = ke / KK - 1, ipre = ke % KK;
            float4 bx = fbox_seg[((size_t)b * NCM1 + cm1) * KK + ipre];
            obox[rank * 4 + 0] = fminf(fmaxf(bx.x, 0.f), 1.f);
            obox[rank * 4 + 1] = fminf(fmaxf(bx.y, 0.f), 1.f);
            obox[rank * 4 + 2] = fminf(fmaxf(bx.z, 0.f), 1.f);
            obox[rank * 4 + 3] = fminf(fmaxf(bx.w, 0.f), 1.f);
            olbl[rank] = (float)(ke / KK);
            osc[rank]  = se;
        }
    }
}

extern "C" void kernel_launch(void* const* d_in, const int* in_sizes, int n_in,
                              void* d_out, int out_size, void* d_ws, size_t ws_size,
                              hipStream_t stream) {
    const float* roi    = (const float*)d_in[0];
    const float* deltas = (const float*)d_in[1];
    const float* probs  = (const float*)d_in[2];
    float* out = (float*)d_out;

    char* base = (char*)d_ws;
    int*    blk_cnt  = (int*)base;                               // 4 KB
    int*    scls     = (int*)(base + 16384);                     // 256 KB
    float2* ssr      = (float2*)(base + 16384 + 262144);         // 512 KB
    SK*     sk_seg   = (SK*)(base + 16384 + 262144 + 524288);    // 2.05 MB
    float4* fbox_seg = (float4*)(base + 16384 + 262144 + 524288 + 2097152); // 4.1 MB

    k_classify<<<GRID, 256, 0, stream>>>(probs, blk_cnt, scls, ssr);
    k_finish<<<NB, 1024, 0, stream>>>(roi, deltas, blk_cnt, scls, ssr,
                                      sk_seg, fbox_seg, out);
}

// Round 16
// 125.585 us; speedup vs baseline: 1.2578x; 1.2004x over previous
//
#include <hip/hip_runtime.h>
#include <math.h>

#pragma clang fp contract(off)

constexpr int NB  = 16;    // batch
constexpr int NR  = 4096;  // rois per image
constexpr int NC  = 81;    // classes (incl. background)
constexpr int NCM1 = NC - 1;              // foreground classes
constexpr int KK  = 200;   // per-class candidate cap == max_total
constexpr int ROWS_PER_BLK = 64;
constexpr int CHUNKS = NR / ROWS_PER_BLK;     // 64 chunks per image
constexpr int GRID = NB * NR / ROWS_PER_BLK;  // 1024 classify blocks
constexpr int MAXC = 1024;                    // per-class LDS candidate cap
constexpr int NBKT = 2048;                    // score histogram buckets
constexpr int PCAP = 2560;                    // LDS pruned-list cap (spill beyond)
constexpr float SCORE_TH = 0.5f;
constexpr float IOU_TH   = 0.5f;
constexpr float EPSF     = 1e-8f;

struct SK { float s; int key; };   // 8B packed (score, cls*KK + prenms_rank)

__device__ __forceinline__ void decode_box(const float4& a, const float4& d,
                                           float& y1, float& x1, float& y2, float& x2) {
    float ah  = a.z - a.x;
    float aw  = a.w - a.y;
    float acy = a.x + 0.5f * ah;
    float acx = a.y + 0.5f * aw;
    float dy = d.x * 0.1f, dx = d.y * 0.1f;
    float dh = d.z * 0.2f, dw = d.w * 0.2f;
    float bh  = expf(dh) * ah;
    float bw  = expf(dw) * aw;
    float bcy = dy * ah + acy;
    float bcx = dx * aw + acx;
    y1 = bcy - 0.5f * bh;
    x1 = bcx - 0.5f * bw;
    y2 = y1 + bh;
    x2 = x1 + bw;
}

// monotone bucket over (0.5, 1]: float bits minus bits(0.5), top mantissa bits
__device__ __forceinline__ int bucketOf(float s) {
    int bk = (int)((__float_as_uint(s) - 0x3F000000u) >> 12);
    return bk < 0 ? 0 : (bk > NBKT - 1 ? NBKT - 1 : bk);
}

// 4 threads/ROI, 64 ROIs/block, 1024 blocks (full device for the 21MB read).
// Emits compact per-chunk candidates (cls, score, roi). Also zeroes img_done.
__global__ void k_classify(const float* __restrict__ probs,
                           int* __restrict__ blk_cnt,
                           int* __restrict__ scls,
                           float2* __restrict__ ssr,
                           int* __restrict__ img_done) {
    __shared__ float lp[ROWS_PER_BLK * NC];   // 20736 B
    __shared__ int wcnt[4], wbase[4];
    const int bid = blockIdx.x, tid = threadIdx.x;

    if (tid == 0 && bid < NB) img_done[bid] = 0;   // poison-proof, every call

    const float4* src = (const float4*)(probs + (size_t)bid * ROWS_PER_BLK * NC);
    float4* dst = (float4*)lp;
    for (int v = tid; v < ROWS_PER_BLK * NC / 4; v += 256) dst[v] = src[v];
    __syncthreads();

    int g = tid >> 2;               // row within block
    int j = tid & 3;                // sub-lane within row group
    const float* row = lp + g * NC;
    float m = -1.0f;
    int am = 127;
    for (int c = j; c < NC; c += 4) {
        float v = row[c];
        if (v > m) { m = v; am = c; }            // first-max within subset
    }
    for (int mask = 1; mask <= 2; mask <<= 1) {  // tie -> smaller idx (jnp.argmax)
        float om = __shfl_xor(m, mask);
        int   oi = __shfl_xor(am, mask);
        if (om > m || (om == m && oi < am)) { m = om; am = oi; }
    }

    bool pred = (j == 0) && (am != 0) && (m > SCORE_TH);
    unsigned long long bal = __ballot(pred);
    int lane = tid & 63, w = tid >> 6;
    if (lane == 0) wcnt[w] = __popcll(bal);
    __syncthreads();
    if (tid == 0) {
        int run = 0;
        for (int i = 0; i < 4; ++i) { wbase[i] = run; run += wcnt[i]; }
        blk_cnt[bid] = run;                      // unconditional: no init pass
    }
    __syncthreads();

    if (pred) {
        int pos = wbase[w] + __popcll(bal & ((1ull << lane) - 1ull));
        int r = bid * ROWS_PER_BLK + g;
        int idx = bid * ROWS_PER_BLK + pos;      // == b*NR + chunk*64 + pos
        scls[idx] = am;
        ssr[idx]  = make_float2(m, (float)(r & (NR - 1)));   // roi exact in f32
    }
}

// One block per (image, fg-class): gather class-c candidates -> LDS stable
// rank -> decode top-200 survivors -> mask-NMS -> fixed (b,c) segments.
// Then threadfence + img_done count; the LAST block of each image runs the
// image-level top-200 (histogram-pruned exact rank) and writes the output.
__global__ __launch_bounds__(256)
void k_pcfin(const float* __restrict__ roi,
             const float* __restrict__ deltas,
             const int* __restrict__ blk_cnt,
             const int* __restrict__ scls,
             const float2* __restrict__ ssr,
             int* __restrict__ kcnt,
             SK* __restrict__ sk_seg,
             float4* __restrict__ fbox_seg,
             SK* __restrict__ spill,
             int* __restrict__ img_done,
             float* __restrict__ out) {
    union SM {
        struct {
            int ccnt[CHUNKS];
            float ls[MAXC], lroi[MAXC];
            float ss[KK], sy1[KK], sx1[KK], sy2[KK], sx2[KK], sar[KK];
            unsigned long long sup[KK][4];
            int skeep[KK];
        } p;                                   // 20.4 KB
        struct {
            int hist[NBKT];                    // 8 KB
            int csum[256];                     // 1 KB
            SK  pl[PCAP];                      // 20 KB
            int pfx[NCM1 + 1];
        } t;                                   // 29.4 KB
    };
    __shared__ SM sm;
    __shared__ int lcnt, lastflag, tshared, pcnt;

    const int bid = blockIdx.x, tid = threadIdx.x;
    const int b = bid / NCM1, cm1 = bid % NCM1, c = cm1 + 1;

    // ---- per-class phase (R13-proven) ----
    if (tid < CHUNKS) sm.p.ccnt[tid] = blk_cnt[b * CHUNKS + tid];
    if (tid == 0) lcnt = 0;
    __syncthreads();

    const int* sc = scls + (size_t)b * NR;
    const float2* sr = ssr + (size_t)b * NR;
    for (int sidx = tid; sidx < NR; sidx += 256) {
        int chunk = sidx >> 6, s = sidx & 63;
        if (s < sm.p.ccnt[chunk] && sc[sidx] == c) {
            int p = atomicAdd(&lcnt, 1);         // LDS atomic; order-free keys
            if (p < MAXC) {
                float2 v = sr[sidx];
                sm.p.ls[p] = v.x; sm.p.lroi[p] = v.y;
            }
        }
    }
    __syncthreads();
    int Mc = lcnt < MAXC ? lcnt : MAXC;
    int L = Mc < KK ? Mc : KK;

    if (Mc > 0) {
        // stable rank by (score desc, roi asc); decode survivors only
        for (int i = tid; i < Mc; i += 256) {
            float si = sm.p.ls[i], ri = sm.p.lroi[i];
            int rank = 0;
            for (int jj = 0; jj < Mc; ++jj) {
                float sj = sm.p.ls[jj], rj = sm.p.lroi[jj];
                rank += (int)((sj > si) | ((sj == si) & (rj < ri)));
            }
            if (rank < KK) {
                int r = (int)ri;
                float4 a = ((const float4*)roi)[(size_t)b * NR + r];
                float4 d = *(const float4*)(deltas + (((size_t)b * NR + r) * NC + c) * 4);
                float y1, x1, y2, x2;
                decode_box(a, d, y1, x1, y2, x2);
                sm.p.ss[rank] = si;
                sm.p.sy1[rank] = y1; sm.p.sx1[rank] = x1;
                sm.p.sy2[rank] = y2; sm.p.sx2[rank] = x2;
                sm.p.sar[rank] = fmaxf(y2 - y1, 0.f) * fmaxf(x2 - x1, 0.f);
            }
        }
        __syncthreads();

        // parallel suppression-mask build: sup[i] = {j>i : IoU(i,j) > TH}
        for (int idx = tid; idx < L * 4; idx += 256) {
            int i = idx >> 2, w = idx & 3;
            int j0 = w * 64;
            unsigned long long bits = 0;
            int jend = j0 + 64 < L ? j0 + 64 : L;
            int jstart = j0 > i + 1 ? j0 : i + 1;
            if (jstart < jend) {
                float yi1 = sm.p.sy1[i], xi1 = sm.p.sx1[i];
                float yi2 = sm.p.sy2[i], xi2 = sm.p.sx2[i], ai = sm.p.sar[i];
                for (int j = jstart; j < jend; ++j) {
                    float yy1 = fmaxf(yi1, sm.p.sy1[j]), xx1 = fmaxf(xi1, sm.p.sx1[j]);
                    float yy2 = fminf(yi2, sm.p.sy2[j]), xx2 = fminf(xi2, sm.p.sx2[j]);
                    float inter = fmaxf(yy2 - yy1, 0.f) * fmaxf(xx2 - xx1, 0.f);
                    float uni = ai + sm.p.sar[j] - inter;
                    if (inter / (uni + EPSF) > IOU_TH) bits |= 1ull << (j - j0);
                }
            }
            sm.p.sup[i][w] = bits;
        }
        __syncthreads();

        // greedy scan on wave 0: keep-bits in registers (4 bits/lane)
        if (tid < 64) {
            int lane = tid;
            int kmask = 0;
            #pragma unroll
            for (int s = 0; s < 4; ++s) if (s * 64 + lane < L) kmask |= 1 << s;
            for (int i = 0; i < L; ++i) {
                int oi = i & 63, si = i >> 6;
                unsigned long long r0 = sm.p.sup[i][0], r1 = sm.p.sup[i][1];
                unsigned long long r2 = sm.p.sup[i][2], r3 = sm.p.sup[i][3];
                int keep_i = (__shfl(kmask, oi) >> si) & 1;   // uniform
                if (keep_i) {
                    int supb = (int)((r0 >> lane) & 1)
                             | ((int)((r1 >> lane) & 1) << 1)
                             | ((int)((r2 >> lane) & 1) << 2)
                             | ((int)((r3 >> lane) & 1) << 3);
                    kmask &= ~supb;
                }
            }
            #pragma unroll
            for (int s = 0; s < 4; ++s) {
                int jj = s * 64 + lane;
                if (jj < L) sm.p.skeep[jj] = (kmask >> s) & 1;
            }
        }
        __syncthreads();

        // sk at post-NMS pos; fbox at PRE-NMS rank i (key-addressable)
        for (int i = tid; i < L; i += 256) {
            if (sm.p.skeep[i]) {
                int pos = 0;
                for (int j = 0; j < i; ++j) pos += sm.p.skeep[j];
                size_t sb = (size_t)bid * KK;
                sk_seg[sb + pos].s = sm.p.ss[i];
                sk_seg[sb + pos].key = c * KK + i;
                fbox_seg[sb + i] = make_float4(sm.p.sy1[i], sm.p.sx1[i],
                                               sm.p.sy2[i], sm.p.sx2[i]);
            }
        }
        if (tid == 0) {
            int tot = 0;
            for (int i = 0; i < L; ++i) tot += sm.p.skeep[i];
            kcnt[bid] = tot;
        }
    } else {
        if (tid == 0) kcnt[bid] = 0;
    }
    __syncthreads();

    // ---- release + count; exactly one block per image proceeds to the tail ----
    __threadfence();                              // publish kcnt/sk_seg/fbox_seg
    if (tid == 0) {
        int v = atomicAdd(&img_done[b], 1);       // device-scope
        lastflag = (v == NCM1 - 1);
    }
    __syncthreads();
    if (!lastflag) return;
    __threadfence();                              // acquire siblings' writes

    // ================= image-level top-200 tail (one block) =================
    if (tid == 0) {
        int run = 0;
        for (int s = 0; s < NCM1; ++s) { sm.t.pfx[s] = run; run += kcnt[b * NCM1 + s]; }
        sm.t.pfx[NCM1] = run;
        pcnt = 0;
    }
    for (int i = tid; i < NBKT; i += 256) sm.t.hist[i] = 0;
    __syncthreads();
    const int M = sm.t.pfx[NCM1];
    const int minKM = M < KK ? M : KK;

    // pass 1: histogram of scores
    for (int i = tid; i < M; i += 256) {
        int lo = 0, hi = NCM1 - 1;
        while (lo < hi) {
            int mid = (lo + hi + 1) >> 1;
            if (sm.t.pfx[mid] <= i) lo = mid; else hi = mid - 1;
        }
        SK v = sk_seg[((size_t)b * NCM1 + lo) * KK + (i - sm.t.pfx[lo])];
        atomicAdd(&sm.t.hist[bucketOf(v.s)], 1);
    }
    __syncthreads();

    // threshold bucket t: smallest suffix covering minKM entries (two-level scan)
    {
        int s8 = 0;
        #pragma unroll
        for (int k = 0; k < NBKT / 256; ++k) s8 += sm.t.hist[tid * (NBKT / 256) + k];
        sm.t.csum[tid] = s8;
    }
    __syncthreads();
    if (tid == 0) {
        int cum = 0, tb = 0;
        for (int ch = 255; ch >= 0; --ch) {
            if (cum + sm.t.csum[ch] >= minKM) {
                for (int bk = ch * (NBKT / 256) + (NBKT / 256) - 1; bk >= ch * (NBKT / 256); --bk) {
                    cum += sm.t.hist[bk];
                    if (cum >= minKM) { tb = bk; break; }
                }
                break;
            }
            cum += sm.t.csum[ch];
        }
        tshared = tb;
    }
    __syncthreads();
    const int tb = tshared;

    // pass 2: gather pruned set (bucket >= tb) into LDS, spill beyond PCAP
    SK* spill_b = spill + (size_t)b * NR;
    for (int i = tid; i < M; i += 256) {
        int lo = 0, hi = NCM1 - 1;
        while (lo < hi) {
            int mid = (lo + hi + 1) >> 1;
            if (sm.t.pfx[mid] <= i) lo = mid; else hi = mid - 1;
        }
        SK v = sk_seg[((size_t)b * NCM1 + lo) * KK + (i - sm.t.pfx[lo])];
        if (bucketOf(v.s) >= tb) {
            int pos = atomicAdd(&pcnt, 1);
            if (pos < PCAP) sm.t.pl[pos] = v;
            else            spill_b[pos] = v;
        }
    }
    __syncthreads();
    const int P = pcnt;                 // pruned set == global top-P (exact)
    const int PL = P < PCAP ? P : PCAP;

    float* obox = out + (size_t)b * KK * 4;
    float* olbl = out + (size_t)NB * KK * 4 + (size_t)b * KK;
    float* osc  = out + (size_t)NB * KK * 5 + (size_t)b * KK;

    // zero the unwritten tail rows (disjoint from ranked writes)
    for (int i = minKM + tid; i < KK; i += 256) {
        obox[i * 4 + 0] = 0.f; obox[i * 4 + 1] = 0.f;
        obox[i * 4 + 2] = 0.f; obox[i * 4 + 3] = 0.f;
        olbl[i] = 0.f; osc[i] = 0.f;
    }

    // pass 3: exact rank within pruned set; rank<KK -> write output row
    const float4* p4 = (const float4*)sm.t.pl;   // 2 SK per float4
    const int npair = PL >> 1;
    for (int ti = tid; ti < P; ti += 256) {
        SK me = (ti < PCAP) ? sm.t.pl[ti] : spill_b[ti];
        float se = me.s; int ke = me.key;
        int rank = 0;
        #pragma unroll 4
        for (int p = 0; p < npair; ++p) {
            float4 v = p4[p];
            int k0 = __float_as_int(v.y), k1 = __float_as_int(v.w);
            rank += (int)((v.x > se) | ((v.x == se) & (k0 < ke)));
            rank += (int)((v.z > se) | ((v.z == se) & (k1 < ke)));
        }
        if (PL & 1) {
            SK v = sm.t.pl[PL - 1];
            rank += (int)((v.s > se) | ((v.s == se) & (v.key < ke)));
        }
        for (int j = PCAP; j < P; ++j) {         // spill part (never in practice)
            SK v = spill_b[j];
            rank += (int)((v.s > se) | ((v.s == se) & (v.key < ke)));
        }
        if (rank < KK) {
            int scm1 = ke / KK - 1, ipre = ke % KK;
            float4 bx = fbox_seg[((size_t)b * NCM1 + scm1) * KK + ipre];
            obox[rank * 4 + 0] = fminf(fmaxf(bx.x, 0.f), 1.f);
            obox[rank * 4 + 1] = fminf(fmaxf(bx.y, 0.f), 1.f);
            obox[rank * 4 + 2] = fminf(fmaxf(bx.z, 0.f), 1.f);
            obox[rank * 4 + 3] = fminf(fmaxf(bx.w, 0.f), 1.f);
            olbl[rank] = (float)(ke / KK);
            osc[rank]  = se;
        }
    }
}

extern "C" void kernel_launch(void* const* d_in, const int* in_sizes, int n_in,
                              void* d_out, int out_size, void* d_ws, size_t ws_size,
                              hipStream_t stream) {
    const float* roi    = (const float*)d_in[0];
    const float* deltas = (const float*)d_in[1];
    const float* probs  = (const float*)d_in[2];
    float* out = (float*)d_out;

    char* base = (char*)d_ws;
    int*    blk_cnt  = (int*)(base);                   // 4 KB
    int*    img_done = (int*)(base + 8192);            // 16 ints
    int*    scls     = (int*)(base + 16384);           // 256 KB
    float2* ssr      = (float2*)(base + 278528);       // 512 KB
    int*    kcnt     = (int*)(base + 802816);          // 5 KB
    SK*     sk_seg   = (SK*)(base + 811008);           // 2.05 MB
    float4* fbox_seg = (float4*)(base + 2908160);      // 4.1 MB
    SK*     spill    = (SK*)(base + 7102464);          // 512 KB

    k_classify<<<GRID, 256, 0, stream>>>(probs, blk_cnt, scls, ssr, img_done);
    k_pcfin<<<NB * NCM1, 256, 0, stream>>>(roi, deltas, blk_cnt, scls, ssr,
                                           kcnt, sk_seg, fbox_seg, spill,
                                           img_done, out);
}

// Round 17
// 69.704 us; speedup vs baseline: 2.2661x; 1.8017x over previous
//
#include <hip/hip_runtime.h>
#include <math.h>

#pragma clang fp contract(off)

constexpr int NB  = 16;    // batch
constexpr int NR  = 4096;  // rois per image
constexpr int NC  = 81;    // classes (incl. background)
constexpr int NCM1 = NC - 1;              // foreground classes
constexpr int KK  = 200;   // per-class candidate cap == max_total
constexpr int CAP = 4096;  // max kept entries per image
constexpr int ROWS_PER_BLK = 64;
constexpr int CHUNKS = NR / ROWS_PER_BLK;     // 64 chunks per image
constexpr int GRID = NB * NR / ROWS_PER_BLK;  // 1024 blocks
constexpr int MAXC = 1024;                    // per-class LDS candidate cap
constexpr int TCHUNK = 512;
constexpr int NCHUNK = CAP / TCHUNK;          // 8 blocks per image
constexpr float SCORE_TH = 0.5f;
constexpr float IOU_TH   = 0.5f;
constexpr float EPSF     = 1e-8f;

struct SK { float s; int key; };   // 8B packed (score, cls*KK + prenms_rank)

__device__ __forceinline__ void decode_box(const float4& a, const float4& d,
                                           float& y1, float& x1, float& y2, float& x2) {
    float ah  = a.z - a.x;
    float aw  = a.w - a.y;
    float acy = a.x + 0.5f * ah;
    float acx = a.y + 0.5f * aw;
    float dy = d.x * 0.1f, dx = d.y * 0.1f;
    float dh = d.z * 0.2f, dw = d.w * 0.2f;
    float bh  = expf(dh) * ah;
    float bw  = expf(dw) * aw;
    float bcy = dy * ah + acy;
    float bcx = dx * aw + acx;
    y1 = bcy - 0.5f * bh;
    x1 = bcx - 0.5f * bw;
    y2 = y1 + bh;
    x2 = x1 + bw;
}

// 4 threads/ROI, 64 ROIs/block. Ballot-compaction into per-block fixed slots:
// blk_cnt[bid] written unconditionally -> no init kernel, no global atomics.
// ssr.y packs cls*4096 + roi (exact in f32, < 2^19).
__global__ void k_classify(const float* __restrict__ roi,
                           const float* __restrict__ deltas,
                           const float* __restrict__ probs,
                           int* __restrict__ blk_cnt,
                           float2* __restrict__ ssr,
                           float4* __restrict__ sbox) {
    __shared__ float lp[ROWS_PER_BLK * NC];   // 20736 B
    __shared__ int wcnt[4], wbase[4];
    const int bid = blockIdx.x, tid = threadIdx.x;

    const float4* src = (const float4*)(probs + (size_t)bid * ROWS_PER_BLK * NC);
    float4* dst = (float4*)lp;
    for (int v = tid; v < ROWS_PER_BLK * NC / 4; v += 256) dst[v] = src[v];
    __syncthreads();

    int g = tid >> 2;               // row within block
    int j = tid & 3;                // sub-lane within row group
    const float* row = lp + g * NC;
    float m = -1.0f;
    int am = 127;
    for (int c = j; c < NC; c += 4) {
        float v = row[c];
        if (v > m) { m = v; am = c; }            // first-max within subset
    }
    for (int mask = 1; mask <= 2; mask <<= 1) {  // tie -> smaller idx (jnp.argmax)
        float om = __shfl_xor(m, mask);
        int   oi = __shfl_xor(am, mask);
        if (om > m || (om == m && oi < am)) { m = om; am = oi; }
    }

    bool pred = (j == 0) && (am != 0) && (m > SCORE_TH);
    unsigned long long bal = __ballot(pred);
    int lane = tid & 63, w = tid >> 6;
    if (lane == 0) wcnt[w] = __popcll(bal);
    __syncthreads();
    if (tid == 0) {
        int run = 0;
        for (int i = 0; i < 4; ++i) { wbase[i] = run; run += wcnt[i]; }
        blk_cnt[bid] = run;
    }
    __syncthreads();

    if (pred) {
        int pos = wbase[w] + __popcll(bal & ((1ull << lane) - 1ull));
        int r = bid * ROWS_PER_BLK + g;
        float4 a = ((const float4*)roi)[r];
        float4 d = *(const float4*)(deltas + ((size_t)r * NC + am) * 4);
        float y1, x1, y2, x2;
        decode_box(a, d, y1, x1, y2, x2);
        int idx = bid * ROWS_PER_BLK + pos;      // == b*NR + chunk*64 + pos
        ssr[idx]  = make_float2(m, (float)(am * 4096 + (r & (NR - 1))));
        sbox[idx] = make_float4(y1, x1, y2, x2);
    }
}

// One block per (image, fg-class): gather class-c candidates via packed-key
// scan -> LDS stable rank -> top-200 -> parallel mask build -> wave-0 greedy
// NMS -> fixed (b,c) segments. sk_seg compacted at post-NMS pos; fbox_seg at
// PRE-NMS rank i (k_topk fetches boxes by key = c*KK+i). kcnt written
// unconditionally -> no init pass, no global atomics.
__global__ void k_perclass(const int* __restrict__ blk_cnt,
                           const float2* __restrict__ ssr,
                           const float4* __restrict__ sbox,
                           int* __restrict__ kcnt,
                           SK* __restrict__ sk_seg,
                           float4* __restrict__ fbox_seg) {
    __shared__ int ccnt[CHUNKS];
    __shared__ int lcnt;
    __shared__ float ls[MAXC], lroi[MAXC];
    __shared__ unsigned short lidx[MAXC];
    __shared__ float ss[KK], sy1[KK], sx1[KK], sy2[KK], sx2[KK], sar[KK];
    __shared__ unsigned long long sup[KK][4];
    __shared__ int skeep[KK];

    const int bid = blockIdx.x, tid = threadIdx.x;
    const int b = bid / NCM1, cm1 = bid % NCM1, c = cm1 + 1;
    const int keybase = c * 4096;

    if (tid < CHUNKS) ccnt[tid] = blk_cnt[b * CHUNKS + tid];
    if (tid == 0) lcnt = 0;
    __syncthreads();

    const float2* sr = ssr + (size_t)b * NR;
    for (int sidx = tid; sidx < NR; sidx += 256) {
        int chunk = sidx >> 6, s = sidx & 63;
        if (s < ccnt[chunk]) {
            float2 v = sr[sidx];
            int key = (int)v.y;
            if ((key >> 12) == c) {
                int p = atomicAdd(&lcnt, 1);     // LDS atomic; order-free keys
                if (p < MAXC) {
                    ls[p] = v.x; lroi[p] = v.y;  // packed key: roi-order within class
                    lidx[p] = (unsigned short)sidx;
                }
            }
        }
    }
    __syncthreads();
    int Mc = lcnt < MAXC ? lcnt : MAXC;
    if (Mc == 0) {
        if (tid == 0) kcnt[bid] = 0;
        return;
    }
    (void)keybase;

    // stable rank by (score desc, roi asc) — lax.top_k order (packed key same order)
    for (int i = tid; i < Mc; i += 256) {
        float si = ls[i], ri = lroi[i];
        int rank = 0;
        for (int jj = 0; jj < Mc; ++jj) {
            float sj = ls[jj], rj = lroi[jj];
            rank += (int)((sj > si) | ((sj == si) & (rj < ri)));
        }
        if (rank < KK) {
            float4 bx = sbox[(size_t)b * NR + lidx[i]];
            ss[rank] = si;
            sy1[rank] = bx.x; sx1[rank] = bx.y; sy2[rank] = bx.z; sx2[rank] = bx.w;
            sar[rank] = fmaxf(bx.z - bx.x, 0.f) * fmaxf(bx.w - bx.y, 0.f);
        }
    }
    __syncthreads();

    int L = Mc < KK ? Mc : KK;

    // parallel suppression-mask build: sup[i] = {j>i : IoU(i,j) > TH}
    for (int idx = tid; idx < L * 4; idx += 256) {
        int i = idx >> 2, w = idx & 3;
        int j0 = w * 64;
        unsigned long long bits = 0;
        int jend = j0 + 64 < L ? j0 + 64 : L;
        int jstart = j0 > i + 1 ? j0 : i + 1;
        if (jstart < jend) {
            float yi1 = sy1[i], xi1 = sx1[i], yi2 = sy2[i], xi2 = sx2[i], ai = sar[i];
            for (int j = jstart; j < jend; ++j) {
                float yy1 = fmaxf(yi1, sy1[j]), xx1 = fmaxf(xi1, sx1[j]);
                float yy2 = fminf(yi2, sy2[j]), xx2 = fminf(xi2, sx2[j]);
                float inter = fmaxf(yy2 - yy1, 0.f) * fmaxf(xx2 - xx1, 0.f);
                float uni = ai + sar[j] - inter;
                if (inter / (uni + EPSF) > IOU_TH) bits |= 1ull << (j - j0);
            }
        }
        sup[i][w] = bits;
    }
    __syncthreads();

    // greedy scan on wave 0: keep-bits in registers (4 bits/lane)
    if (tid < 64) {
        int lane = tid;
        int kmask = 0;
        #pragma unroll
        for (int s = 0; s < 4; ++s) if (s * 64 + lane < L) kmask |= 1 << s;
        for (int i = 0; i < L; ++i) {
            int oi = i & 63, si = i >> 6;
            unsigned long long r0 = sup[i][0], r1 = sup[i][1];
            unsigned long long r2 = sup[i][2], r3 = sup[i][3];
            int keep_i = (__shfl(kmask, oi) >> si) & 1;   // uniform across wave
            if (keep_i) {
                int supb = (int)((r0 >> lane) & 1)
                         | ((int)((r1 >> lane) & 1) << 1)
                         | ((int)((r2 >> lane) & 1) << 2)
                         | ((int)((r3 >> lane) & 1) << 3);
                kmask &= ~supb;
            }
        }
        #pragma unroll
        for (int s = 0; s < 4; ++s) {
            int jj = s * 64 + lane;
            if (jj < L) skeep[jj] = (kmask >> s) & 1;
        }
    }
    __syncthreads();

    // write kept: sk compacted at pos; fbox at PRE-NMS rank i (key-addressable)
    for (int i = tid; i < L; i += 256) {
        if (skeep[i]) {
            int pos = 0;
            for (int j = 0; j < i; ++j) pos += skeep[j];
            size_t segbase = (size_t)bid * KK;
            sk_seg[segbase + pos].s = ss[i];
            sk_seg[segbase + pos].key = c * KK + i;
            fbox_seg[segbase + i] = make_float4(sy1[i], sx1[i], sy2[i], sx2[i]);
        }
    }
    if (tid == 0) {
        int tot = 0;
        for (int i = 0; i < L; ++i) tot += skeep[i];
        kcnt[bid] = tot;
    }
}

// NCHUNK(=8) blocks per image, 512 threads: prefix over 80 class counts ->
// gather compact (score,key) list into LDS (binary-search segment lookup) ->
// each thread ranks ONE entry (float4 = 2 entries/read) -> direct scatter
// write (ranks unique & dense). Box by key: cm1 = ke/KK - 1, i = ke%KK.
__global__ __launch_bounds__(512)
void k_topk(const int* __restrict__ kcnt,
            const SK* __restrict__ sk_seg,
            const float4* __restrict__ fbox_seg,
            float* __restrict__ out) {
    int b = blockIdx.x / NCHUNK, chunk = blockIdx.x % NCHUNK;
    const int tid = threadIdx.x;

    __shared__ int pfx[NCM1 + 1];
    __shared__ SK  sL[CAP];   // 32 KB packed (score,key)

    if (tid < NCM1) pfx[tid + 1] = kcnt[b * NCM1 + tid];
    if (tid == 0) pfx[0] = 0;
    __syncthreads();
    if (tid == 0) {
        int run = 0;
        for (int s = 1; s <= NCM1; ++s) { run += pfx[s]; pfx[s] = run; }
    }
    __syncthreads();
    int M = pfx[NCM1];

    float* obox = out + (size_t)b * KK * 4;
    float* olbl = out + (size_t)NB * KK * 4 + (size_t)b * KK;
    float* osc  = out + (size_t)NB * KK * 5 + (size_t)b * KK;

    if (chunk == 0) {   // zero the unwritten tail every call (deterministic output)
        int Mi = M < KK ? M : KK;
        for (int i = Mi + tid; i < KK; i += 512) {
            obox[i * 4 + 0] = 0.f; obox[i * 4 + 1] = 0.f;
            obox[i * 4 + 2] = 0.f; obox[i * 4 + 3] = 0.f;
            olbl[i] = 0.f; osc[i] = 0.f;
        }
    }
    if (chunk * TCHUNK >= M) return;

    // gather compact list: binary search segment for each compact index
    for (int i = tid; i < M; i += 512) {
        int lo = 0, hi = NCM1 - 1;        // find lo: pfx[lo] <= i < pfx[lo+1]
        while (lo < hi) {
            int mid = (lo + hi + 1) >> 1;
            if (pfx[mid] <= i) lo = mid; else hi = mid - 1;
        }
        int k = i - pfx[lo];
        sL[i] = sk_seg[((size_t)b * NCM1 + lo) * KK + k];
    }
    __syncthreads();

    int e = chunk * TCHUNK + tid;
    if (e >= M) return;
    float se = sL[e].s; int ke = sL[e].key;
    int rank = 0;
    const float4* p4 = (const float4*)sL;   // 2 SK per float4
    int npair = M >> 1;
    #pragma unroll 4
    for (int p = 0; p < npair; ++p) {
        float4 v = p4[p];
        int k0 = __float_as_int(v.y), k1 = __float_as_int(v.w);
        rank += (int)((v.x > se) | ((v.x == se) & (k0 < ke)));
        rank += (int)((v.z > se) | ((v.z == se) & (k1 < ke)));
    }
    if (M & 1) {
        float sj = sL[M - 1].s; int kj = sL[M - 1].key;
        rank += (int)((sj > se) | ((sj == se) & (kj < ke)));
    }
    if (rank < KK) {
        int cm1 = ke / KK - 1, ipre = ke % KK;
        float4 bx = fbox_seg[((size_t)b * NCM1 + cm1) * KK + ipre];
        obox[rank * 4 + 0] = fminf(fmaxf(bx.x, 0.f), 1.f);
        obox[rank * 4 + 1] = fminf(fmaxf(bx.y, 0.f), 1.f);
        obox[rank * 4 + 2] = fminf(fmaxf(bx.z, 0.f), 1.f);
        obox[rank * 4 + 3] = fminf(fmaxf(bx.w, 0.f), 1.f);
        olbl[rank] = (float)(ke / KK);
        osc[rank]  = se;
    }
}

extern "C" void kernel_launch(void* const* d_in, const int* in_sizes, int n_in,
                              void* d_out, int out_size, void* d_ws, size_t ws_size,
                              hipStream_t stream) {
    const float* roi    = (const float*)d_in[0];
    const float* deltas = (const float*)d_in[1];
    const float* probs  = (const float*)d_in[2];
    float* out = (float*)d_out;

    char* base = (char*)d_ws;
    int*    blk_cnt  = (int*)base;                               // 4 KB
    int*    kcnt     = (int*)(base + 4096);                      // 16*80 ints
    float2* ssr      = (float2*)(base + 16384);                  // 512 KB
    float4* sbox     = (float4*)(base + 16384 + 524288);         // 1 MB
    SK*     sk_seg   = (SK*)(base + 16384 + 524288 + 1048576);   // 2.05 MB
    float4* fbox_seg = (float4*)(base + 16384 + 524288 + 1048576 + 2097152); // 4.1 MB

    k_classify<<<GRID, 256, 0, stream>>>(roi, deltas, probs, blk_cnt, ssr, sbox);
    k_perclass<<<NB * NCM1, 256, 0, stream>>>(blk_cnt, ssr, sbox,
                                              kcnt, sk_seg, fbox_seg);
    k_topk<<<NB * NCHUNK, 512, 0, stream>>>(kcnt, sk_seg, fbox_seg, out);
}